// Round 10
// baseline (129.340 us; speedup 1.0000x reference)
//
#include <hip/hip_runtime.h>
#include <hip/hip_bf16.h>

// Problem constants (AttentionalPlanarRemapping): N=32, C=64, H=W=128, E=512
#define NB   32
#define CC   64
#define HW   16384          // 128*128
#define EE   512
#define CC2  4096           // C*C
#define SR2  260            // LDS row stride (u16); 260%8==4 -> lh halves on disjoint banks

using short8  = __attribute__((ext_vector_type(8))) short;
using f32x16  = __attribute__((ext_vector_type(16))) float;

// fp32 -> bf16 round-to-nearest-even
__device__ __forceinline__ unsigned short f2bf(float x) {
    unsigned int u = __float_as_uint(x);
    u += 0x7FFFu + ((u >> 16) & 1u);
    return (unsigned short)(u >> 16);
}

// ---------------------------------------------------------------------------
// Kernel 1: logits[n][j] = dot(atts[n,:], W[j,:]) + b[j]   (unchanged)
// ---------------------------------------------------------------------------
__global__ __launch_bounds__(256) void logits_kernel(
    const float* __restrict__ atts, const float* __restrict__ W,
    const float* __restrict__ b, float* __restrict__ logits) {
    const int t  = threadIdx.x;
    const int j  = blockIdx.x * 2 + (t & 1);
    const int n  = (t >> 1) & 31;
    const int kq = t >> 6;                 // 0..3
    const float* __restrict__ wrow = W + (size_t)j * EE + kq * 128;
    const float* __restrict__ arow = atts + (size_t)n * EE + kq * 128;
    float acc0 = 0.f, acc1 = 0.f;
    #pragma unroll
    for (int k = 0; k < 128; k += 8) {
        float4 w0 = *reinterpret_cast<const float4*>(wrow + k);
        float4 a0 = *reinterpret_cast<const float4*>(arow + k);
        float4 w1 = *reinterpret_cast<const float4*>(wrow + k + 4);
        float4 a1 = *reinterpret_cast<const float4*>(arow + k + 4);
        acc0 = fmaf(w0.x, a0.x, acc0); acc0 = fmaf(w0.y, a0.y, acc0);
        acc0 = fmaf(w0.z, a0.z, acc0); acc0 = fmaf(w0.w, a0.w, acc0);
        acc1 = fmaf(w1.x, a1.x, acc1); acc1 = fmaf(w1.y, a1.y, acc1);
        acc1 = fmaf(w1.z, a1.z, acc1); acc1 = fmaf(w1.w, a1.w, acc1);
    }
    __shared__ float part[256];
    part[t] = acc0 + acc1;
    __syncthreads();
    if (t < 64) {
        const int jj = blockIdx.x * 2 + (t & 1);
        const int nn = t >> 1;
        const float r = part[t] + part[t + 64] + part[t + 128] + part[t + 192];
        logits[(size_t)nn * CC2 + jj] = r + b[jj];
    }
}

// ---------------------------------------------------------------------------
// Kernel 2: double softmax, packed A output (unchanged):
//   a_pk[n][ks][half][l][e] = a[n][c=32*half+(l&31)][k=ks*16+(l>>5)*8+e]
// ---------------------------------------------------------------------------
__global__ __launch_bounds__(256) void softmax_kernel(
    const float* __restrict__ logits, unsigned short* __restrict__ a_pk) {
    const int n = blockIdx.x;
    const int t = threadIdx.x;
    __shared__ float s[CC2];
    __shared__ float wmax[4];
    __shared__ float wsum[4];

    const float* __restrict__ L = logits + (size_t)n * CC2;

    float lmax = -1e30f;
    for (int i = t; i < CC2; i += 256) {
        float v = L[i];
        s[i] = v;
        lmax = fmaxf(lmax, v);
    }
    #pragma unroll
    for (int off = 32; off > 0; off >>= 1) lmax = fmaxf(lmax, __shfl_xor(lmax, off));
    if ((t & 63) == 0) wmax[t >> 6] = lmax;
    __syncthreads();
    const float bmax = fmaxf(fmaxf(wmax[0], wmax[1]), fmaxf(wmax[2], wmax[3]));

    float lsum = 0.f;
    for (int i = t; i < CC2; i += 256) {
        float e = __expf(s[i] - bmax);
        s[i] = e;
        lsum += e;
    }
    #pragma unroll
    for (int off = 32; off > 0; off >>= 1) lsum += __shfl_xor(lsum, off);
    if ((t & 63) == 0) wsum[t >> 6] = lsum;
    __syncthreads();
    const float inv = 1.f / (wsum[0] + wsum[1] + wsum[2] + wsum[3]);

    for (int i = t; i < CC2; i += 256) s[i] *= inv;
    __syncthreads();

    const int c = t >> 2;          // 0..63
    const int q = t & 3;           // ks = 0..3
    const float* __restrict__ row = s + c * CC + q * 16;
    float mx = -1e30f;
    #pragma unroll
    for (int i = 0; i < 16; ++i) mx = fmaxf(mx, row[i]);
    mx = fmaxf(mx, __shfl_xor(mx, 1));
    mx = fmaxf(mx, __shfl_xor(mx, 2));
    float sum = 0.f;
    #pragma unroll
    for (int i = 0; i < 16; ++i) sum += __expf(row[i] - mx);
    sum += __shfl_xor(sum, 1);
    sum += __shfl_xor(sum, 2);
    const float isum = 1.f / sum;

    union { uint4 u[2]; unsigned short h[16]; } pk;
    #pragma unroll
    for (int i = 0; i < 16; ++i) pk.h[i] = f2bf(__expf(row[i] - mx) * isum);

    const int half = c >> 5;
    const int lc2  = c & 31;
    unsigned short* __restrict__ base =
        a_pk + (size_t)n * CC2 + (size_t)(q * 2 + half) * 512;
    *reinterpret_cast<uint4*>(base + lc2 * 8)        = pk.u[0];
    *reinterpret_cast<uint4*>(base + (32 + lc2) * 8) = pk.u[1];
}

// ---------------------------------------------------------------------------
// Kernel 3 (MFMA, PERSISTENT blocks, register-prefetch pipeline):
//   out[n,c,px] = sum_d a[n,c,d] * img[n,d,px]
// grid 512 blocks (exactly 2/CU, all resident) x 512 thr (8 waves).
// Block owns n = bid>>4 and px range (bid&15)*1024; loops over 4 tiles of
// [64 d][256 px]. Per iter: cvt regs->LDS(buf), ISSUE NEXT TILE'S LOADS
// (outstanding across barrier+compute+stores => ~100%% load duty cycle),
// barrier, 8x mfma_32x32x16_bf16 (b-frag = 32 ds_read_u16, bank-clean via
// SR2 pad), direct nontemporal dword stores. One barrier per tile
// (double-buffer: iter i+2's writes separated from iter i's reads by bar@i+1).
// A-fragments hoisted once per block (n fixed). LDS 66.5 KB -> 2 blocks/CU.
// ---------------------------------------------------------------------------
__global__ __launch_bounds__(512, 4) void einsum_kernel(
    const float* __restrict__ img, const unsigned short* __restrict__ a_pk,
    float* __restrict__ out) {
    const int t    = threadIdx.x;
    const int lane = t & 63;
    const int wv   = t >> 6;                   // wave 0..7
    const int lh   = lane >> 5;
    const int lc   = lane & 31;

    const int n      = blockIdx.x >> 4;        // 0..31
    const int px_blk = (blockIdx.x & 15) * 1024;

    __shared__ __align__(16) unsigned short sB[2 * CC * SR2];   // 66560 B

    const float* __restrict__ gbase = img + (size_t)n * (CC * HW);
    const unsigned short* __restrict__ apn = a_pk + (size_t)n * CC2;

    // per-thread staging coords: wave-instr = one full 1 KB row segment
    const int srow = t >> 6;                   // + i*8 -> d row
    const int scol = (t & 63) * 4;             // px within 256-tile

    // ---- prologue: issue tile-0 loads ----
    float4 v[8];
    #pragma unroll
    for (int i = 0; i < 8; ++i)
        v[i] = *reinterpret_cast<const float4*>(
            gbase + (size_t)(srow + i * 8) * HW + px_blk + scol);

    // ---- hoist A-fragments (L2-hot, 1 KB/wave each) ----
    short8 afrag[8];
    #pragma unroll
    for (int i = 0; i < 8; ++i)
        afrag[i] = *reinterpret_cast<const short8*>(apn + i * 512 + lane * 8);

    int buf = 0;
    for (int it = 0; it < 4; ++it) {
        const int px0 = px_blk + it * 256;

        // ---- cvt + LDS write of current tile ----
        unsigned short* __restrict__ dst = sB + buf * (CC * SR2);
        #pragma unroll
        for (int i = 0; i < 8; ++i) {
            union { uint2 u; unsigned short h4[4]; } pk;
            pk.h4[0] = f2bf(v[i].x); pk.h4[1] = f2bf(v[i].y);
            pk.h4[2] = f2bf(v[i].z); pk.h4[3] = f2bf(v[i].w);
            *reinterpret_cast<uint2*>(&dst[(srow + i * 8) * SR2 + scol]) = pk.u;
        }

        // ---- issue next tile's loads (overlap barrier+compute+stores) ----
        if (it < 3) {
            #pragma unroll
            for (int i = 0; i < 8; ++i)
                v[i] = *reinterpret_cast<const float4*>(
                    gbase + (size_t)(srow + i * 8) * HW + px_blk + (it + 1) * 256 + scol);
        }
        __syncthreads();

        // ---- compute: 4 k-steps x 2 c-halves ----
        f32x16 acc0 = {}, acc1 = {};
        const unsigned short* __restrict__ sb = sB + buf * (CC * SR2);
        const int pxw = wv * 32 + lc;
        #pragma unroll
        for (int ks = 0; ks < 4; ++ks) {
            union { short8 vv; unsigned short sh[8]; } b;
            #pragma unroll
            for (int e = 0; e < 8; ++e)
                b.sh[e] = sb[(ks * 16 + lh * 8 + e) * SR2 + pxw];
            acc0 = __builtin_amdgcn_mfma_f32_32x32x16_bf16(afrag[ks * 2 + 0], b.vv, acc0, 0, 0, 0);
            acc1 = __builtin_amdgcn_mfma_f32_32x32x16_bf16(afrag[ks * 2 + 1], b.vv, acc1, 0, 0, 0);
        }

        // ---- direct nontemporal stores (fire-and-forget) ----
        float* __restrict__ op = out + (size_t)n * (CC * HW) + px0 + pxw;
        #pragma unroll
        for (int r = 0; r < 16; ++r) {
            const int row = (r & 3) + 8 * (r >> 2) + 4 * lh;
            __builtin_nontemporal_store(acc0[r], op + (size_t)row * HW);
            __builtin_nontemporal_store(acc1[r], op + (size_t)(row + 32) * HW);
        }
        buf ^= 1;
    }
}

// ---------------------------------------------------------------------------
extern "C" void kernel_launch(void* const* d_in, const int* in_sizes, int n_in,
                              void* d_out, int out_size, void* d_ws, size_t ws_size,
                              hipStream_t stream) {
    const float* images = (const float*)d_in[0];   // [32,64,128,128]
    const float* atts   = (const float*)d_in[1];   // [32,512]
    const float* W      = (const float*)d_in[2];   // [4096,512]
    const float* b      = (const float*)d_in[3];   // [4096]
    float* out = (float*)d_out;                    // [32,64,128,128]

    // workspace: logits f32 [32*4096] (512 KB) then a_pk bf16 [32*4096] (256 KB)
    float* logits = (float*)d_ws;
    unsigned short* a_pk = (unsigned short*)(logits + NB * CC2);

    logits_kernel<<<CC2 / 2, 256, 0, stream>>>(atts, W, b, logits);
    softmax_kernel<<<NB, 256, 0, stream>>>(logits, a_pk);
    einsum_kernel<<<NB * 16, 512, 0, stream>>>(images, a_pk, out);
}

// Round 11
// 95.992 us; speedup vs baseline: 1.3474x; 1.3474x over previous
//
#include <hip/hip_runtime.h>
#include <hip/hip_bf16.h>

// Problem constants (AttentionalPlanarRemapping): N=32, C=64, H=W=128, E=512
#define NB   32
#define CC   64
#define HW   16384          // 128*128
#define EE   512
#define CC2  4096           // C*C
#define SR3  1036           // LDS row stride (u16): 8*2072 B == 64 (mod 128) -> lh halves on disjoint bank-halves

using short8  = __attribute__((ext_vector_type(8))) short;
using f32x16  = __attribute__((ext_vector_type(16))) float;

// fp32 -> bf16 round-to-nearest-even
__device__ __forceinline__ unsigned short f2bf(float x) {
    unsigned int u = __float_as_uint(x);
    u += 0x7FFFu + ((u >> 16) & 1u);
    return (unsigned short)(u >> 16);
}

// ---------------------------------------------------------------------------
// Kernel 1: logits[n][j] = dot(atts[n,:], W[j,:]) + b[j]   (unchanged)
// ---------------------------------------------------------------------------
__global__ __launch_bounds__(256) void logits_kernel(
    const float* __restrict__ atts, const float* __restrict__ W,
    const float* __restrict__ b, float* __restrict__ logits) {
    const int t  = threadIdx.x;
    const int j  = blockIdx.x * 2 + (t & 1);
    const int n  = (t >> 1) & 31;
    const int kq = t >> 6;                 // 0..3
    const float* __restrict__ wrow = W + (size_t)j * EE + kq * 128;
    const float* __restrict__ arow = atts + (size_t)n * EE + kq * 128;
    float acc0 = 0.f, acc1 = 0.f;
    #pragma unroll
    for (int k = 0; k < 128; k += 8) {
        float4 w0 = *reinterpret_cast<const float4*>(wrow + k);
        float4 a0 = *reinterpret_cast<const float4*>(arow + k);
        float4 w1 = *reinterpret_cast<const float4*>(wrow + k + 4);
        float4 a1 = *reinterpret_cast<const float4*>(arow + k + 4);
        acc0 = fmaf(w0.x, a0.x, acc0); acc0 = fmaf(w0.y, a0.y, acc0);
        acc0 = fmaf(w0.z, a0.z, acc0); acc0 = fmaf(w0.w, a0.w, acc0);
        acc1 = fmaf(w1.x, a1.x, acc1); acc1 = fmaf(w1.y, a1.y, acc1);
        acc1 = fmaf(w1.z, a1.z, acc1); acc1 = fmaf(w1.w, a1.w, acc1);
    }
    __shared__ float part[256];
    part[t] = acc0 + acc1;
    __syncthreads();
    if (t < 64) {
        const int jj = blockIdx.x * 2 + (t & 1);
        const int nn = t >> 1;
        const float r = part[t] + part[t + 64] + part[t + 128] + part[t + 192];
        logits[(size_t)nn * CC2 + jj] = r + b[jj];
    }
}

// ---------------------------------------------------------------------------
// Kernel 2: double softmax, packed A output (unchanged):
//   a_pk[n][ks][half][l][e] = a[n][c=32*half+(l&31)][k=ks*16+(l>>5)*8+e]
// ---------------------------------------------------------------------------
__global__ __launch_bounds__(256) void softmax_kernel(
    const float* __restrict__ logits, unsigned short* __restrict__ a_pk) {
    const int n = blockIdx.x;
    const int t = threadIdx.x;
    __shared__ float s[CC2];
    __shared__ float wmax[4];
    __shared__ float wsum[4];

    const float* __restrict__ L = logits + (size_t)n * CC2;

    float lmax = -1e30f;
    for (int i = t; i < CC2; i += 256) {
        float v = L[i];
        s[i] = v;
        lmax = fmaxf(lmax, v);
    }
    #pragma unroll
    for (int off = 32; off > 0; off >>= 1) lmax = fmaxf(lmax, __shfl_xor(lmax, off));
    if ((t & 63) == 0) wmax[t >> 6] = lmax;
    __syncthreads();
    const float bmax = fmaxf(fmaxf(wmax[0], wmax[1]), fmaxf(wmax[2], wmax[3]));

    float lsum = 0.f;
    for (int i = t; i < CC2; i += 256) {
        float e = __expf(s[i] - bmax);
        s[i] = e;
        lsum += e;
    }
    #pragma unroll
    for (int off = 32; off > 0; off >>= 1) lsum += __shfl_xor(lsum, off);
    if ((t & 63) == 0) wsum[t >> 6] = lsum;
    __syncthreads();
    const float inv = 1.f / (wsum[0] + wsum[1] + wsum[2] + wsum[3]);

    for (int i = t; i < CC2; i += 256) s[i] *= inv;
    __syncthreads();

    const int c = t >> 2;          // 0..63
    const int q = t & 3;           // ks = 0..3
    const float* __restrict__ row = s + c * CC + q * 16;
    float mx = -1e30f;
    #pragma unroll
    for (int i = 0; i < 16; ++i) mx = fmaxf(mx, row[i]);
    mx = fmaxf(mx, __shfl_xor(mx, 1));
    mx = fmaxf(mx, __shfl_xor(mx, 2));
    float sum = 0.f;
    #pragma unroll
    for (int i = 0; i < 16; ++i) sum += __expf(row[i] - mx);
    sum += __shfl_xor(sum, 1);
    sum += __shfl_xor(sum, 2);
    const float isum = 1.f / sum;

    union { uint4 u[2]; unsigned short h[16]; } pk;
    #pragma unroll
    for (int i = 0; i < 16; ++i) pk.h[i] = f2bf(__expf(row[i] - mx) * isum);

    const int half = c >> 5;
    const int lc2  = c & 31;
    unsigned short* __restrict__ base =
        a_pk + (size_t)n * CC2 + (size_t)(q * 2 + half) * 512;
    *reinterpret_cast<uint4*>(base + lc2 * 8)        = pk.u[0];
    *reinterpret_cast<uint4*>(base + (32 + lc2) * 8) = pk.u[1];
}

// ---------------------------------------------------------------------------
// Kernel 3 (MFMA, k-quartered [16 d][1024 px] tiles -> 4-KB HBM chunks):
//   out[n,c,px] = sum_d a[n,c,d] * img[n,d,px]
// grid (16 windows, 32 n) x 1024 thr (16 waves). Per quarter q (k=q*16..+15):
//   cvt regs->LDS[buf] ; issue quarter q+1 loads (4x float4/thread, each
//   wave-instr = 1 KB contiguous, 4 KB spatial bursts per image row) ;
//   load 2 A-frags ; barrier ; 2 col-tiles x 2 c-halves MFMA from LDS.
// Double-buffered LDS (66.3 KB), 4 barriers/block, loads always in flight.
// Writes: block covers 1024 consecutive px for all 64 c -> L2 assembles 4-KB
// dirty runs per output row (nontemporal dword stores).
// acc = 4 x f32x16 = 64 regs; ~110 VGPR -> 4 waves/SIMD cap via
// __launch_bounds__(1024,4). Bank-clean: SR3=1036 u16 (lh offset 64 B mod 128).
// ---------------------------------------------------------------------------
__global__ __launch_bounds__(1024, 4) void einsum_kernel(
    const float* __restrict__ img, const unsigned short* __restrict__ a_pk,
    float* __restrict__ out) {
    const int t    = threadIdx.x;
    const int lane = t & 63;
    const int wv   = t >> 6;                   // wave 0..15
    const int lh   = lane >> 5;
    const int lc   = lane & 31;
    const int n    = blockIdx.y;
    const int px0  = blockIdx.x * 1024;

    __shared__ __align__(16) unsigned short sB[2 * 16 * SR3];   // 66304 B

    const float* __restrict__ gbase = img + (size_t)n * (CC * HW) + px0;
    const unsigned short* __restrict__ apn = a_pk + (size_t)n * CC2;

    // staging coords: quarter-row = (t>>8)+i*4 (0..15), col = (t&255)*4 (0..1020)
    const int qrow = t >> 8;                   // 0..3
    const int col  = (t & 255) * 4;

    const int pxw0 = wv * 64 + lc;             // col-tile 0
    const int pxw1 = pxw0 + 32;                // col-tile 1

    f32x16 acc00 = {}, acc01 = {}, acc10 = {}, acc11 = {};

    // prologue: issue quarter-0 loads
    float4 v[4];
    #pragma unroll
    for (int i = 0; i < 4; ++i)
        v[i] = *reinterpret_cast<const float4*>(
            gbase + (size_t)(qrow + i * 4) * HW + col);

    int buf = 0;
    #pragma unroll
    for (int q = 0; q < 4; ++q) {
        // ---- cvt current quarter into LDS[buf] ----
        unsigned short* __restrict__ dst = sB + buf * (16 * SR3);
        #pragma unroll
        for (int i = 0; i < 4; ++i) {
            union { uint2 u; unsigned short h4[4]; } pk;
            pk.h4[0] = f2bf(v[i].x); pk.h4[1] = f2bf(v[i].y);
            pk.h4[2] = f2bf(v[i].z); pk.h4[3] = f2bf(v[i].w);
            *reinterpret_cast<uint2*>(&dst[(qrow + i * 4) * SR3 + col]) = pk.u;
        }

        // ---- issue next quarter's loads (stay in flight across barrier+compute) ----
        if (q < 3) {
            #pragma unroll
            for (int i = 0; i < 4; ++i)
                v[i] = *reinterpret_cast<const float4*>(
                    gbase + (size_t)((q + 1) * 16 + qrow + i * 4) * HW + col);
        }

        // ---- A-fragments for this k-step (L1/L2-hot, 8 KB per n) ----
        const short8 a0 = *reinterpret_cast<const short8*>(apn + (q * 2 + 0) * 512 + lane * 8);
        const short8 a1 = *reinterpret_cast<const short8*>(apn + (q * 2 + 1) * 512 + lane * 8);

        __syncthreads();

        // ---- compute: 2 col-tiles x 2 c-halves ----
        const unsigned short* __restrict__ sb = sB + buf * (16 * SR3);
        union { short8 vv; unsigned short sh[8]; } b0, b1;
        #pragma unroll
        for (int e = 0; e < 8; ++e) {
            b0.sh[e] = sb[(lh * 8 + e) * SR3 + pxw0];
            b1.sh[e] = sb[(lh * 8 + e) * SR3 + pxw1];
        }
        acc00 = __builtin_amdgcn_mfma_f32_32x32x16_bf16(a0, b0.vv, acc00, 0, 0, 0);
        acc10 = __builtin_amdgcn_mfma_f32_32x32x16_bf16(a1, b0.vv, acc10, 0, 0, 0);
        acc01 = __builtin_amdgcn_mfma_f32_32x32x16_bf16(a0, b1.vv, acc01, 0, 0, 0);
        acc11 = __builtin_amdgcn_mfma_f32_32x32x16_bf16(a1, b1.vv, acc11, 0, 0, 0);

        buf ^= 1;
    }

    // ---- stores: nontemporal dwords; block-aggregate = 4-KB runs per c-row ----
    float* __restrict__ op0 = out + (size_t)n * (CC * HW) + px0 + pxw0;
    float* __restrict__ op1 = out + (size_t)n * (CC * HW) + px0 + pxw1;
    #pragma unroll
    for (int r = 0; r < 16; ++r) {
        const int row = (r & 3) + 8 * (r >> 2) + 4 * lh;
        __builtin_nontemporal_store(acc00[r], op0 + (size_t)row * HW);
        __builtin_nontemporal_store(acc10[r], op0 + (size_t)(row + 32) * HW);
        __builtin_nontemporal_store(acc01[r], op1 + (size_t)row * HW);
        __builtin_nontemporal_store(acc11[r], op1 + (size_t)(row + 32) * HW);
    }
}

// ---------------------------------------------------------------------------
extern "C" void kernel_launch(void* const* d_in, const int* in_sizes, int n_in,
                              void* d_out, int out_size, void* d_ws, size_t ws_size,
                              hipStream_t stream) {
    const float* images = (const float*)d_in[0];   // [32,64,128,128]
    const float* atts   = (const float*)d_in[1];   // [32,512]
    const float* W      = (const float*)d_in[2];   // [4096,512]
    const float* b      = (const float*)d_in[3];   // [4096]
    float* out = (float*)d_out;                    // [32,64,128,128]

    // workspace: logits f32 [32*4096] (512 KB) then a_pk bf16 [32*4096] (256 KB)
    float* logits = (float*)d_ws;
    unsigned short* a_pk = (unsigned short*)(logits + NB * CC2);

    logits_kernel<<<CC2 / 2, 256, 0, stream>>>(atts, W, b, logits);
    softmax_kernel<<<NB, 256, 0, stream>>>(logits, a_pk);
    einsum_kernel<<<dim3(HW / 1024, NB), 1024, 0, stream>>>(images, a_pk, out);
}

// Round 12
// 92.884 us; speedup vs baseline: 1.3925x; 1.0335x over previous
//
#include <hip/hip_runtime.h>
#include <hip/hip_bf16.h>

// Problem constants (AttentionalPlanarRemapping): N=32, C=64, H=W=128, E=512
#define NB   32
#define CC   64
#define HW   16384          // 128*128
#define EE   512
#define CC2  4096           // C*C

using short8  = __attribute__((ext_vector_type(8))) short;
using f32x16  = __attribute__((ext_vector_type(16))) float;

// fp32 -> bf16 round-to-nearest-even
__device__ __forceinline__ unsigned short f2bf(float x) {
    unsigned int u = __float_as_uint(x);
    u += 0x7FFFu + ((u >> 16) & 1u);
    return (unsigned short)(u >> 16);
}

// ---------------------------------------------------------------------------
// Kernel 1: logits[n][j] = dot(atts[n,:], W[j,:]) + b[j]   (unchanged)
// ---------------------------------------------------------------------------
__global__ __launch_bounds__(256) void logits_kernel(
    const float* __restrict__ atts, const float* __restrict__ W,
    const float* __restrict__ b, float* __restrict__ logits) {
    const int t  = threadIdx.x;
    const int j  = blockIdx.x * 2 + (t & 1);
    const int n  = (t >> 1) & 31;
    const int kq = t >> 6;                 // 0..3
    const float* __restrict__ wrow = W + (size_t)j * EE + kq * 128;
    const float* __restrict__ arow = atts + (size_t)n * EE + kq * 128;
    float acc0 = 0.f, acc1 = 0.f;
    #pragma unroll
    for (int k = 0; k < 128; k += 8) {
        float4 w0 = *reinterpret_cast<const float4*>(wrow + k);
        float4 a0 = *reinterpret_cast<const float4*>(arow + k);
        float4 w1 = *reinterpret_cast<const float4*>(wrow + k + 4);
        float4 a1 = *reinterpret_cast<const float4*>(arow + k + 4);
        acc0 = fmaf(w0.x, a0.x, acc0); acc0 = fmaf(w0.y, a0.y, acc0);
        acc0 = fmaf(w0.z, a0.z, acc0); acc0 = fmaf(w0.w, a0.w, acc0);
        acc1 = fmaf(w1.x, a1.x, acc1); acc1 = fmaf(w1.y, a1.y, acc1);
        acc1 = fmaf(w1.z, a1.z, acc1); acc1 = fmaf(w1.w, a1.w, acc1);
    }
    __shared__ float part[256];
    part[t] = acc0 + acc1;
    __syncthreads();
    if (t < 64) {
        const int jj = blockIdx.x * 2 + (t & 1);
        const int nn = t >> 1;
        const float r = part[t] + part[t + 64] + part[t + 128] + part[t + 192];
        logits[(size_t)nn * CC2 + jj] = r + b[jj];
    }
}

// ---------------------------------------------------------------------------
// Kernel 2: double softmax, packed A output (unchanged):
//   a_pk[n][ks][half][l][e] = a[n][c=32*half+(l&31)][k=ks*16+(l>>5)*8+e]
// ---------------------------------------------------------------------------
__global__ __launch_bounds__(256) void softmax_kernel(
    const float* __restrict__ logits, unsigned short* __restrict__ a_pk) {
    const int n = blockIdx.x;
    const int t = threadIdx.x;
    __shared__ float s[CC2];
    __shared__ float wmax[4];
    __shared__ float wsum[4];

    const float* __restrict__ L = logits + (size_t)n * CC2;

    float lmax = -1e30f;
    for (int i = t; i < CC2; i += 256) {
        float v = L[i];
        s[i] = v;
        lmax = fmaxf(lmax, v);
    }
    #pragma unroll
    for (int off = 32; off > 0; off >>= 1) lmax = fmaxf(lmax, __shfl_xor(lmax, off));
    if ((t & 63) == 0) wmax[t >> 6] = lmax;
    __syncthreads();
    const float bmax = fmaxf(fmaxf(wmax[0], wmax[1]), fmaxf(wmax[2], wmax[3]));

    float lsum = 0.f;
    for (int i = t; i < CC2; i += 256) {
        float e = __expf(s[i] - bmax);
        s[i] = e;
        lsum += e;
    }
    #pragma unroll
    for (int off = 32; off > 0; off >>= 1) lsum += __shfl_xor(lsum, off);
    if ((t & 63) == 0) wsum[t >> 6] = lsum;
    __syncthreads();
    const float inv = 1.f / (wsum[0] + wsum[1] + wsum[2] + wsum[3]);

    for (int i = t; i < CC2; i += 256) s[i] *= inv;
    __syncthreads();

    const int c = t >> 2;          // 0..63
    const int q = t & 3;           // ks = 0..3
    const float* __restrict__ row = s + c * CC + q * 16;
    float mx = -1e30f;
    #pragma unroll
    for (int i = 0; i < 16; ++i) mx = fmaxf(mx, row[i]);
    mx = fmaxf(mx, __shfl_xor(mx, 1));
    mx = fmaxf(mx, __shfl_xor(mx, 2));
    float sum = 0.f;
    #pragma unroll
    for (int i = 0; i < 16; ++i) sum += __expf(row[i] - mx);
    sum += __shfl_xor(sum, 1);
    sum += __shfl_xor(sum, 2);
    const float isum = 1.f / sum;

    union { uint4 u[2]; unsigned short h[16]; } pk;
    #pragma unroll
    for (int i = 0; i < 16; ++i) pk.h[i] = f2bf(__expf(row[i] - mx) * isum);

    const int half = c >> 5;
    const int lc2  = c & 31;
    unsigned short* __restrict__ base =
        a_pk + (size_t)n * CC2 + (size_t)(q * 2 + half) * 512;
    *reinterpret_cast<uint4*>(base + lc2 * 8)        = pk.u[0];
    *reinterpret_cast<uint4*>(base + (32 + lc2) * 8) = pk.u[1];
}

// ---------------------------------------------------------------------------
// Kernel 3 (MFMA + LDS-staged B; EXACT R6 structure, the best measured at
// 76.5 us — with ONE controlled change: REGULAR stores instead of
// nontemporal. Theory: nt out-writes were evicting img from Infinity Cache
// every replay (FETCH_SIZE pinned at 66 MB); regular stores absorb into L3,
// img becomes L3-resident, steady-state reads stop paying HBM.
// grid (64 px-tiles, 32 n) x 512 thr (8 waves). Tile = [64 d][256 px].
// ---------------------------------------------------------------------------
__global__ __launch_bounds__(512) void einsum_kernel(
    const float* __restrict__ img, const unsigned short* __restrict__ a_pk,
    float* __restrict__ out) {
    const int t    = threadIdx.x;
    const int lane = t & 63;
    const int wv   = t >> 6;                   // wave 0..7
    const int n    = blockIdx.y;
    const int px0  = blockIdx.x * 256;
    const int lh   = lane >> 5;                // k-group half
    const int lc   = lane & 31;

    __shared__ unsigned short sImg[CC * 256];  // [d][px] bf16, 32 KB

    // ---- stage: 8 independent float4 loads, then cvt + b64 LDS writes ----
    {
        const int px_l = (t & 63) * 4;         // 0..252
        const int d0   = (t >> 6) * 8;         // 0,8,..,56
        const float* __restrict__ gp = img + (size_t)n * (CC * HW) + px0 + px_l;
        float4 v0 = *reinterpret_cast<const float4*>(gp + (size_t)(d0 + 0) * HW);
        float4 v1 = *reinterpret_cast<const float4*>(gp + (size_t)(d0 + 1) * HW);
        float4 v2 = *reinterpret_cast<const float4*>(gp + (size_t)(d0 + 2) * HW);
        float4 v3 = *reinterpret_cast<const float4*>(gp + (size_t)(d0 + 3) * HW);
        float4 v4 = *reinterpret_cast<const float4*>(gp + (size_t)(d0 + 4) * HW);
        float4 v5 = *reinterpret_cast<const float4*>(gp + (size_t)(d0 + 5) * HW);
        float4 v6 = *reinterpret_cast<const float4*>(gp + (size_t)(d0 + 6) * HW);
        float4 v7 = *reinterpret_cast<const float4*>(gp + (size_t)(d0 + 7) * HW);
        union { uint2 u; unsigned short h[4]; } pk;
        #define STG(i, vv) \
            pk.h[0] = f2bf(vv.x); pk.h[1] = f2bf(vv.y); \
            pk.h[2] = f2bf(vv.z); pk.h[3] = f2bf(vv.w); \
            *reinterpret_cast<uint2*>(&sImg[(d0 + i) * 256 + px_l]) = pk.u;
        STG(0, v0) STG(1, v1) STG(2, v2) STG(3, v3)
        STG(4, v4) STG(5, v5) STG(6, v6) STG(7, v7)
        #undef STG
    }
    __syncthreads();

    // ---- compute ----
    const int px_w = wv * 32 + lc;
    const unsigned short* __restrict__ apn = a_pk + (size_t)n * CC2;

    f32x16 acc0 = {};   // c = 0..31
    f32x16 acc1 = {};   // c = 32..63

    #pragma unroll
    for (int ks = 0; ks < 4; ++ks) {
        const int kbase = ks * 16 + lh * 8;
        union { short8 v; unsigned short h[8]; } bf;
        #pragma unroll
        for (int e = 0; e < 8; ++e)
            bf.h[e] = sImg[(kbase + e) * 256 + px_w];
        short8 a0 = *reinterpret_cast<const short8*>(apn + (ks * 2 + 0) * 512 + lane * 8);
        short8 a1 = *reinterpret_cast<const short8*>(apn + (ks * 2 + 1) * 512 + lane * 8);
        acc0 = __builtin_amdgcn_mfma_f32_32x32x16_bf16(a0, bf.v, acc0, 0, 0, 0);
        acc1 = __builtin_amdgcn_mfma_f32_32x32x16_bf16(a1, bf.v, acc1, 0, 0, 0);
    }

    // ---- REGULAR stores (the single change vs R6) ----
    float* __restrict__ op = out + (size_t)n * (CC * HW) + px0 + px_w;
    #pragma unroll
    for (int r = 0; r < 16; ++r) {
        const int row = (r & 3) + 8 * (r >> 2) + 4 * lh;
        op[(size_t)row * HW]        = acc0[r];
        op[(size_t)(row + 32) * HW] = acc1[r];
    }
}

// ---------------------------------------------------------------------------
extern "C" void kernel_launch(void* const* d_in, const int* in_sizes, int n_in,
                              void* d_out, int out_size, void* d_ws, size_t ws_size,
                              hipStream_t stream) {
    const float* images = (const float*)d_in[0];   // [32,64,128,128]
    const float* atts   = (const float*)d_in[1];   // [32,512]
    const float* W      = (const float*)d_in[2];   // [4096,512]
    const float* b      = (const float*)d_in[3];   // [4096]
    float* out = (float*)d_out;                    // [32,64,128,128]

    // workspace: logits f32 [32*4096] (512 KB) then a_pk bf16 [32*4096] (256 KB)
    float* logits = (float*)d_ws;
    unsigned short* a_pk = (unsigned short*)(logits + NB * CC2);

    logits_kernel<<<CC2 / 2, 256, 0, stream>>>(atts, W, b, logits);
    softmax_kernel<<<NB, 256, 0, stream>>>(logits, a_pk);
    einsum_kernel<<<dim3(HW / 256, NB), 512, 0, stream>>>(images, a_pk, out);
}